// Round 17
// baseline (152.457 us; speedup 1.0000x reference)
//
#include <hip/hip_runtime.h>
#include <hip/hip_bf16.h>
#include <stdint.h>

#define N_NODES_C 131072
#define B_C       16384
#define IN_C      1024
#define OUT_C     512
#define NC_C      16

typedef short s16x8 __attribute__((ext_vector_type(8)));
typedef float f32x4 __attribute__((ext_vector_type(4)));

__device__ __forceinline__ unsigned short f2bf(float f) {
  union { float f; unsigned u; } v; v.f = f;
  unsigned u = v.u;
  unsigned r = (u + 0x7fffu + ((u >> 16) & 1u)) >> 16;  // RNE
  return (unsigned short)r;
}

__device__ __forceinline__ void async_cp16(void* lds, const void* g) {
  __builtin_amdgcn_global_load_lds(
      (const __attribute__((address_space(1))) unsigned int*)g,
      (__attribute__((address_space(3))) unsigned int*)lds, 16, 0, 0);
}

// wave64 sum-reduce on the VALU pipe via DPP. Result in lane 63. [R12 verified]
__device__ __forceinline__ float dpp_reduce_add(float x) {
  float t;
  t = __int_as_float(__builtin_amdgcn_update_dpp(0, __float_as_int(x), 0x111, 0xf, 0xf, false)); x += t;
  t = __int_as_float(__builtin_amdgcn_update_dpp(0, __float_as_int(x), 0x112, 0xf, 0xf, false)); x += t;
  t = __int_as_float(__builtin_amdgcn_update_dpp(0, __float_as_int(x), 0x114, 0xf, 0xf, false)); x += t;
  t = __int_as_float(__builtin_amdgcn_update_dpp(0, __float_as_int(x), 0x118, 0xf, 0xf, false)); x += t;
  t = __int_as_float(__builtin_amdgcn_update_dpp(0, __float_as_int(x), 0x142, 0xa, 0xf, false)); x += t;  // row_bcast15
  t = __int_as_float(__builtin_amdgcn_update_dpp(0, __float_as_int(x), 0x143, 0xc, 0xf, false)); x += t;  // row_bcast31
  return x;
}

// ---- fused: 512 blocks; each block ROUTES 32 rows then CONVERTS its W chunk.
// [R16 verified, unchanged]
__global__ __launch_bounds__(512) void k_fused(
    const float* __restrict__ W, unsigned short* __restrict__ Wb,
    const float* __restrict__ gnn_x, const float* __restrict__ Wc,
    const int* __restrict__ batch, const int* __restrict__ ego_idx,
    unsigned short* __restrict__ xb, int* __restrict__ rows_sorted,
    int* __restrict__ cursors) {
  __shared__ float wc[NC_C * IN_C];  // 64 KiB
  __shared__ int sbest[32];
  __shared__ int sbase[16];

  const int bid = blockIdx.x;
  const int t = threadIdx.x;

  for (int i = t * 4; i < NC_C * IN_C; i += 512 * 4)
    *(float4*)&wc[i] = *(const float4*)&Wc[i];
  __syncthreads();

  const int w = t >> 6, l = t & 63;
  const int gbase = bid * 32;
  const int gw = gbase + w * 4;  // 4 rows per wave

  const int gq = gw + (l & 3);
  int lo = 0, hi = N_NODES_C;
  while (lo < hi) { int mid = (lo + hi) >> 1; if (batch[mid] < gq) lo = mid + 1; else hi = mid; }
  const int srcq = lo + ego_idx[gq];

  #pragma unroll
  for (int rr = 0; rr < 4; ++rr) {
    const int g = gw + rr;
    const int src_row = __shfl(srcq, rr, 64);
    const float* xp = gnn_x + (size_t)src_row * IN_C;

    float4 xv[4];
    #pragma unroll
    for (int j = 0; j < 4; ++j) xv[j] = *(const float4*)&xp[j * 256 + l * 4];

    unsigned short* dst = &xb[(size_t)g * IN_C];
    #pragma unroll
    for (int j = 0; j < 4; ++j) {
      ushort4 h;
      h.x = f2bf(xv[j].x); h.y = f2bf(xv[j].y); h.z = f2bf(xv[j].z); h.w = f2bf(xv[j].w);
      *(ushort4*)&dst[j * 256 + l * 4] = h;
    }

    float sc[NC_C];
    #pragma unroll
    for (int c = 0; c < NC_C; ++c) {
      float a = 0.f;
      #pragma unroll
      for (int j = 0; j < 4; ++j) {
        float4 wv = *(const float4*)&wc[c * IN_C + j * 256 + l * 4];
        a += xv[j].x * wv.x + xv[j].y * wv.y + xv[j].z * wv.z + xv[j].w * wv.w;
      }
      sc[c] = dpp_reduce_add(a);
    }
    if (l == 63) {
      int best = 0; float bv = sc[0];
      #pragma unroll
      for (int c = 1; c < NC_C; ++c) if (sc[c] > bv) { bv = sc[c]; best = c; }  // first-max, matches np
      sbest[w * 4 + rr] = best;
    }
  }

  __syncthreads();
  if (t < 16) {
    int n = 0;
    #pragma unroll
    for (int r = 0; r < 32; ++r) n += (sbest[r] == t);
    if (n) sbase[t] = atomicAdd(&cursors[t * 16], n);
  }
  __syncthreads();
  if (t < 32) {
    const int c = sbest[t];
    int rank = 0;
    for (int r = 0; r < t; ++r) rank += (sbest[r] == c);
    rows_sorted[c * B_C + sbase[c] + rank] = gbase + t;
  }

  // convert this block's W chunk: 16384 floats
  const size_t wbase = (size_t)bid * 16384;
  #pragma unroll
  for (int i = t * 4; i < 16384; i += 512 * 4) {
    float4 v = *(const float4*)&W[wbase + i];
    ushort4 h;
    h.x = f2bf(v.x); h.y = f2bf(v.y); h.z = f2bf(v.z); h.w = f2bf(v.w);
    *(ushort4*)&Wb[wbase + i] = h;
  }
}

// ---- grouped GEMM: out[rid] = xb[rid] @ W[e]^T ----  [R10 verified, unchanged]
__global__ __launch_bounds__(512) void k_gemm(
    const unsigned short* __restrict__ xb, const unsigned short* __restrict__ Wb,
    const int* __restrict__ rows_sorted, const int* __restrict__ cnts,
    float* __restrict__ out) {
  const int i = blockIdx.x + 4 * blockIdx.y + 512 * blockIdx.z;  // 0..8191
  const int xcd = i & 7;
  const int j = i >> 3;
  const int e = xcd * 2 + (j & 1);
  const int r = j >> 1;
  const int mt = r >> 2;
  const int nt = r & 3;

  const int cnt = cnts[e * 16];
  const int m0 = mt * 128;
  if (m0 >= cnt) return;
  const int n0 = nt * 128;

  __shared__ unsigned short Al[2][128 * 64];
  __shared__ unsigned short Bl[2][128 * 64];

  const int t = threadIdx.x;
  const int w = t >> 6, l = t & 63;

  const int srow = t >> 3;
  const int scolb = (t & 7) * 16;
  const char* bbase = (const char*)Wb + ((size_t)e * OUT_C + n0) * (IN_C * 2);
  const char* aptr[2];
  const char* bptr[2];
  #pragma unroll
  for (int ii = 0; ii < 2; ++ii) {
    const int row = srow + ii * 64;
    const int sw = scolb ^ ((row & 7) << 4);
    const int p = m0 + row;
    const int rid = (p < cnt) ? rows_sorted[e * B_C + p] : 0;
    aptr[ii] = (const char*)xb + (size_t)rid * (IN_C * 2) + sw;
    bptr[ii] = bbase + (size_t)row * (IN_C * 2) + sw;
  }

  const f32x4 fz = {0.f, 0.f, 0.f, 0.f};
  f32x4 acc[2][4];
  #pragma unroll
  for (int mi = 0; mi < 2; ++mi)
    #pragma unroll
    for (int ni = 0; ni < 4; ++ni) acc[mi][ni] = fz;

#define STAGE(buf, kt) do {                                        \
    char* ab_ = (char*)&Al[buf][0] + w * 1024;                     \
    char* bb_ = (char*)&Bl[buf][0] + w * 1024;                     \
    const size_t ko_ = (size_t)(kt) * 128;                         \
    _Pragma("unroll")                                              \
    for (int i_ = 0; i_ < 2; ++i_) {                               \
      async_cp16(ab_ + i_ * 8192, aptr[i_] + ko_);                 \
      async_cp16(bb_ + i_ * 8192, bptr[i_] + ko_);                 \
    }                                                              \
  } while (0)

  STAGE(0, 0);
  __syncthreads();

  const int wm = w >> 1, wn = w & 1;
  const int lrow = l & 15, kg = l >> 4;
  const int NKT = IN_C / 64;  // 16

  int cur = 0;
  for (int kt = 0; kt < NKT; ++kt) {
    if (kt + 1 < NKT) STAGE(cur ^ 1, kt + 1);
    #pragma unroll
    for (int ks = 0; ks < 2; ++ks) {
      const int cb = ks * 64 + kg * 16;
      s16x8 a[2], b[4];
      #pragma unroll
      for (int mi = 0; mi < 2; ++mi) {
        const int row = wm * 32 + mi * 16 + lrow;
        a[mi] = *(const s16x8*)((const char*)&Al[cur][0] + row * 128 + (cb ^ ((row & 7) << 4)));
      }
      #pragma unroll
      for (int ni = 0; ni < 4; ++ni) {
        const int row = wn * 64 + ni * 16 + lrow;
        b[ni] = *(const s16x8*)((const char*)&Bl[cur][0] + row * 128 + (cb ^ ((row & 7) << 4)));
      }
      #pragma unroll
      for (int mi = 0; mi < 2; ++mi)
        #pragma unroll
        for (int ni = 0; ni < 4; ++ni)
          acc[mi][ni] = __builtin_amdgcn_mfma_f32_16x16x32_bf16(a[mi], b[ni], acc[mi][ni], 0, 0, 0);
    }
    __syncthreads();
    cur ^= 1;
  }
#undef STAGE

  #pragma unroll
  for (int mi = 0; mi < 2; ++mi) {
    #pragma unroll
    for (int reg = 0; reg < 4; ++reg) {
      const int p = m0 + wm * 32 + mi * 16 + kg * 4 + reg;
      if (p < cnt) {
        const int rid = rows_sorted[e * B_C + p];
        float* orow = out + (size_t)rid * OUT_C + n0 + wn * 64 + lrow;
        #pragma unroll
        for (int ni = 0; ni < 4; ++ni) orow[ni * 16] = acc[mi][ni][reg];
      }
    }
  }
}

extern "C" void kernel_launch(void* const* d_in, const int* in_sizes, int n_in,
                              void* d_out, int out_size, void* d_ws, size_t ws_size,
                              hipStream_t stream) {
  const float* gnn_x     = (const float*)d_in[0];
  const float* Wc        = (const float*)d_in[1];
  const float* W_experts = (const float*)d_in[2];
  const int*   batch     = (const int*)d_in[3];
  const int*   ego_idx   = (const int*)d_in[4];
  float* out = (float*)d_out;

  uint8_t* ws = (uint8_t*)d_ws;
  unsigned short* xb     = (unsigned short*)ws;                     // 33.5 MB bf16 ego rows (by g)
  unsigned short* W_bf16 = (unsigned short*)(ws + 33554432);        // 16.8 MB
  int* rows_sorted = (int*)(ws + 50331648);                         // 1 MB
  int* cursors     = (int*)(ws + 51380224);                         // 1 KB (16 centers x 64B)

  hipMemsetAsync(cursors, 0, NC_C * 16 * sizeof(int), stream);
  k_fused<<<dim3(512), dim3(512), 0, stream>>>(W_experts, W_bf16, gnn_x, Wc,
                                               batch, ego_idx, xb, rows_sorted, cursors);
  // DIAGNOSTIC ROUND: k_gemm launched 3x (idempotent -- pure function of its
  // inputs, deterministic). t_gemm = (dur_us - 80.0) / 2 gives per-kernel
  // attribution the fill-crowded profiler top-5 can't.
  k_gemm<<<dim3(OUT_C / 128, B_C / 128, NC_C), dim3(512), 0, stream>>>(xb, W_bf16, rows_sorted, cursors, out);
  k_gemm<<<dim3(OUT_C / 128, B_C / 128, NC_C), dim3(512), 0, stream>>>(xb, W_bf16, rows_sorted, cursors, out);
  k_gemm<<<dim3(OUT_C / 128, B_C / 128, NC_C), dim3(512), 0, stream>>>(xb, W_bf16, rows_sorted, cursors, out);
}

// Round 18
// 79.737 us; speedup vs baseline: 1.9120x; 1.9120x over previous
//
#include <hip/hip_runtime.h>
#include <hip/hip_bf16.h>
#include <stdint.h>

#define N_NODES_C 131072
#define B_C       16384
#define IN_C      1024
#define OUT_C     512
#define NC_C      16

typedef short s16x8 __attribute__((ext_vector_type(8)));
typedef float f32x4 __attribute__((ext_vector_type(4)));

__device__ __forceinline__ unsigned short f2bf(float f) {
  union { float f; unsigned u; } v; v.f = f;
  unsigned u = v.u;
  unsigned r = (u + 0x7fffu + ((u >> 16) & 1u)) >> 16;  // RNE
  return (unsigned short)r;
}

__device__ __forceinline__ void async_cp16(void* lds, const void* g) {
  __builtin_amdgcn_global_load_lds(
      (const __attribute__((address_space(1))) unsigned int*)g,
      (__attribute__((address_space(3))) unsigned int*)lds, 16, 0, 0);
}

// wave64 sum-reduce on the VALU pipe via DPP. Result in lane 63. [R12 verified]
__device__ __forceinline__ float dpp_reduce_add(float x) {
  float t;
  t = __int_as_float(__builtin_amdgcn_update_dpp(0, __float_as_int(x), 0x111, 0xf, 0xf, false)); x += t;
  t = __int_as_float(__builtin_amdgcn_update_dpp(0, __float_as_int(x), 0x112, 0xf, 0xf, false)); x += t;
  t = __int_as_float(__builtin_amdgcn_update_dpp(0, __float_as_int(x), 0x114, 0xf, 0xf, false)); x += t;
  t = __int_as_float(__builtin_amdgcn_update_dpp(0, __float_as_int(x), 0x118, 0xf, 0xf, false)); x += t;
  t = __int_as_float(__builtin_amdgcn_update_dpp(0, __float_as_int(x), 0x142, 0xa, 0xf, false)); x += t;  // row_bcast15
  t = __int_as_float(__builtin_amdgcn_update_dpp(0, __float_as_int(x), 0x143, 0xc, 0xf, false)); x += t;  // row_bcast31
  return x;
}

// ---- fused: 512 blocks; each block ROUTES 32 rows then CONVERTS its W chunk.
// [R16 verified, unchanged]
__global__ __launch_bounds__(512) void k_fused(
    const float* __restrict__ W, unsigned short* __restrict__ Wb,
    const float* __restrict__ gnn_x, const float* __restrict__ Wc,
    const int* __restrict__ batch, const int* __restrict__ ego_idx,
    unsigned short* __restrict__ xb, int* __restrict__ rows_sorted,
    int* __restrict__ cursors) {
  __shared__ float wc[NC_C * IN_C];  // 64 KiB
  __shared__ int sbest[32];
  __shared__ int sbase[16];

  const int bid = blockIdx.x;
  const int t = threadIdx.x;

  for (int i = t * 4; i < NC_C * IN_C; i += 512 * 4)
    *(float4*)&wc[i] = *(const float4*)&Wc[i];
  __syncthreads();

  const int w = t >> 6, l = t & 63;
  const int gbase = bid * 32;
  const int gw = gbase + w * 4;  // 4 rows per wave

  const int gq = gw + (l & 3);
  int lo = 0, hi = N_NODES_C;
  while (lo < hi) { int mid = (lo + hi) >> 1; if (batch[mid] < gq) lo = mid + 1; else hi = mid; }
  const int srcq = lo + ego_idx[gq];

  #pragma unroll
  for (int rr = 0; rr < 4; ++rr) {
    const int g = gw + rr;
    const int src_row = __shfl(srcq, rr, 64);
    const float* xp = gnn_x + (size_t)src_row * IN_C;

    float4 xv[4];
    #pragma unroll
    for (int j = 0; j < 4; ++j) xv[j] = *(const float4*)&xp[j * 256 + l * 4];

    unsigned short* dst = &xb[(size_t)g * IN_C];
    #pragma unroll
    for (int j = 0; j < 4; ++j) {
      ushort4 h;
      h.x = f2bf(xv[j].x); h.y = f2bf(xv[j].y); h.z = f2bf(xv[j].z); h.w = f2bf(xv[j].w);
      *(ushort4*)&dst[j * 256 + l * 4] = h;
    }

    float sc[NC_C];
    #pragma unroll
    for (int c = 0; c < NC_C; ++c) {
      float a = 0.f;
      #pragma unroll
      for (int j = 0; j < 4; ++j) {
        float4 wv = *(const float4*)&wc[c * IN_C + j * 256 + l * 4];
        a += xv[j].x * wv.x + xv[j].y * wv.y + xv[j].z * wv.z + xv[j].w * wv.w;
      }
      sc[c] = dpp_reduce_add(a);
    }
    if (l == 63) {
      int best = 0; float bv = sc[0];
      #pragma unroll
      for (int c = 1; c < NC_C; ++c) if (sc[c] > bv) { bv = sc[c]; best = c; }  // first-max, matches np
      sbest[w * 4 + rr] = best;
    }
  }

  __syncthreads();
  if (t < 16) {
    int n = 0;
    #pragma unroll
    for (int r = 0; r < 32; ++r) n += (sbest[r] == t);
    if (n) sbase[t] = atomicAdd(&cursors[t * 16], n);
  }
  __syncthreads();
  if (t < 32) {
    const int c = sbest[t];
    int rank = 0;
    for (int r = 0; r < t; ++r) rank += (sbest[r] == c);
    rows_sorted[c * B_C + sbase[c] + rank] = gbase + t;
  }

  // convert this block's W chunk: 16384 floats
  const size_t wbase = (size_t)bid * 16384;
  #pragma unroll
  for (int i = t * 4; i < 16384; i += 512 * 4) {
    float4 v = *(const float4*)&W[wbase + i];
    ushort4 h;
    h.x = f2bf(v.x); h.y = f2bf(v.y); h.z = f2bf(v.z); h.w = f2bf(v.w);
    *(ushort4*)&Wb[wbase + i] = h;
  }
}

// ---- grouped GEMM: out[rid] = xb[rid] @ W[e]^T ----
// R10 structure + NEW counted-vmcnt pipeline: 3 LDS buffers (48 KB), prologue
// stages tiles 0,1; per K-step {STAGE(kt+2); MFMA(kt); vmcnt(4); s_barrier}.
// Same ONE barrier/step as R10, but the wait covers only the PREVIOUS step's
// 4 loads (had a full step to land) -- this step's loads fly across the
// barrier. MFMA k-order bit-identical to R10. XCD-affine decode kept.
__global__ __launch_bounds__(512) void k_gemm(
    const unsigned short* __restrict__ xb, const unsigned short* __restrict__ Wb,
    const int* __restrict__ rows_sorted, const int* __restrict__ cnts,
    float* __restrict__ out) {
  const int i = blockIdx.x + 4 * blockIdx.y + 512 * blockIdx.z;  // 0..8191
  const int xcd = i & 7;
  const int j = i >> 3;
  const int e = xcd * 2 + (j & 1);
  const int r = j >> 1;
  const int mt = r >> 2;
  const int nt = r & 3;

  const int cnt = cnts[e * 16];
  const int m0 = mt * 128;
  if (m0 >= cnt) return;
  const int n0 = nt * 128;

  __shared__ unsigned short Al[3][128 * 64];  // 16 KiB per buf
  __shared__ unsigned short Bl[3][128 * 64];

  const int t = threadIdx.x;
  const int w = t >> 6, l = t & 63;

  const int srow = t >> 3;
  const int scolb = (t & 7) * 16;
  const char* bbase = (const char*)Wb + ((size_t)e * OUT_C + n0) * (IN_C * 2);
  const char* aptr[2];
  const char* bptr[2];
  #pragma unroll
  for (int ii = 0; ii < 2; ++ii) {
    const int row = srow + ii * 64;
    const int sw = scolb ^ ((row & 7) << 4);
    const int p = m0 + row;
    const int rid = (p < cnt) ? rows_sorted[e * B_C + p] : 0;
    aptr[ii] = (const char*)xb + (size_t)rid * (IN_C * 2) + sw;
    bptr[ii] = bbase + (size_t)row * (IN_C * 2) + sw;
  }

  const f32x4 fz = {0.f, 0.f, 0.f, 0.f};
  f32x4 acc[2][4];
  #pragma unroll
  for (int mi = 0; mi < 2; ++mi)
    #pragma unroll
    for (int ni = 0; ni < 4; ++ni) acc[mi][ni] = fz;

#define STAGE(buf, kt) do {                                        \
    char* ab_ = (char*)&Al[buf][0] + w * 1024;                     \
    char* bb_ = (char*)&Bl[buf][0] + w * 1024;                     \
    const size_t ko_ = (size_t)(kt) * 128;                         \
    _Pragma("unroll")                                              \
    for (int i_ = 0; i_ < 2; ++i_) {                               \
      async_cp16(ab_ + i_ * 8192, aptr[i_] + ko_);                 \
      async_cp16(bb_ + i_ * 8192, bptr[i_] + ko_);                 \
    }                                                              \
  } while (0)

  // prologue: 2 tiles in flight; wait for tile 0 (4 loads group) only
  STAGE(0, 0);
  STAGE(1, 1);
  asm volatile("s_waitcnt vmcnt(4)" ::: "memory");
  __builtin_amdgcn_s_barrier();
  asm volatile("" ::: "memory");

  const int wm = w >> 1, wn = w & 1;
  const int lrow = l & 15, kg = l >> 4;
  const int NKT = IN_C / 64;  // 16

  for (int kt = 0; kt < NKT; ++kt) {
    const int cbuf = kt % 3;
    if (kt + 2 < NKT) STAGE((kt + 2) % 3, kt + 2);

    #pragma unroll
    for (int ks = 0; ks < 2; ++ks) {
      const int cb = ks * 64 + kg * 16;
      s16x8 a[2], b[4];
      #pragma unroll
      for (int mi = 0; mi < 2; ++mi) {
        const int row = wm * 32 + mi * 16 + lrow;
        a[mi] = *(const s16x8*)((const char*)&Al[cbuf][0] + row * 128 + (cb ^ ((row & 7) << 4)));
      }
      #pragma unroll
      for (int ni = 0; ni < 4; ++ni) {
        const int row = wn * 64 + ni * 16 + lrow;
        b[ni] = *(const s16x8*)((const char*)&Bl[cbuf][0] + row * 128 + (cb ^ ((row & 7) << 4)));
      }
      #pragma unroll
      for (int mi = 0; mi < 2; ++mi)
        #pragma unroll
        for (int ni = 0; ni < 4; ++ni)
          acc[mi][ni] = __builtin_amdgcn_mfma_f32_16x16x32_bf16(a[mi], b[ni], acc[mi][ni], 0, 0, 0);
    }

    if (kt + 1 < NKT) {
      if (kt + 2 < NKT) {
        asm volatile("s_waitcnt vmcnt(4)" ::: "memory");  // kt+1's loads done; kt+2's fly on
      } else {
        asm volatile("s_waitcnt vmcnt(0)" ::: "memory");  // tail drain
      }
      __builtin_amdgcn_s_barrier();
      asm volatile("" ::: "memory");
    }
  }
#undef STAGE

  #pragma unroll
  for (int mi = 0; mi < 2; ++mi) {
    #pragma unroll
    for (int reg = 0; reg < 4; ++reg) {
      const int p = m0 + wm * 32 + mi * 16 + kg * 4 + reg;
      if (p < cnt) {
        const int rid = rows_sorted[e * B_C + p];
        float* orow = out + (size_t)rid * OUT_C + n0 + wn * 64 + lrow;
        #pragma unroll
        for (int ni = 0; ni < 4; ++ni) orow[ni * 16] = acc[mi][ni][reg];
      }
    }
  }
}

extern "C" void kernel_launch(void* const* d_in, const int* in_sizes, int n_in,
                              void* d_out, int out_size, void* d_ws, size_t ws_size,
                              hipStream_t stream) {
  const float* gnn_x     = (const float*)d_in[0];
  const float* Wc        = (const float*)d_in[1];
  const float* W_experts = (const float*)d_in[2];
  const int*   batch     = (const int*)d_in[3];
  const int*   ego_idx   = (const int*)d_in[4];
  float* out = (float*)d_out;

  uint8_t* ws = (uint8_t*)d_ws;
  unsigned short* xb     = (unsigned short*)ws;                     // 33.5 MB bf16 ego rows (by g)
  unsigned short* W_bf16 = (unsigned short*)(ws + 33554432);        // 16.8 MB
  int* rows_sorted = (int*)(ws + 50331648);                         // 1 MB
  int* cursors     = (int*)(ws + 51380224);                         // 1 KB (16 centers x 64B)

  hipMemsetAsync(cursors, 0, NC_C * 16 * sizeof(int), stream);
  k_fused<<<dim3(512), dim3(512), 0, stream>>>(W_experts, W_bf16, gnn_x, Wc,
                                               batch, ego_idx, xb, rows_sorted, cursors);
  k_gemm<<<dim3(OUT_C / 128, B_C / 128, NC_C), dim3(512), 0, stream>>>(xb, W_bf16, rows_sorted, cursors, out);
}